// Round 7
// baseline (4260.638 us; speedup 1.0000x reference)
//
#include <hip/hip_runtime.h>
#include <hip/hip_bf16.h>
#include <cstdint>

// Neural-ODE RK4, v7: v6 dataflow + L2-cached consumer reads.
// v6 post-mortem: 40 MB/eval of sc0sc1 (L2-bypassing) reads saturate the L3
// coherent fabric (~3 TB/s) -> that WAS the 13.3us/eval. v7: data reads are
// plain cached loads; all global stores remain write-through sc0 sc1 (L2 never
// dirty), and each phase entry does poll -> buffer_inv sc0 sc1 (LLVM's
// agent-acquire) in wave 0 before __syncthreads releases the loads. Because
// blockIdx%8 XCD round-robin puts all 32 blocks of an XCD in one row group,
// the 32 blocks share one 128 KB h-slice through their XCD's L2.
//
// Sync (unchanged from v6): per-eval epoch flags, single writer each:
//   A(e): wait fB[mg][*]>=e -> inv -> read yin -> h tile -> fA[mg][g16]=e
//   B(e): wait fA[mg][*]>=e -> inv -> read h   -> RK4    -> fB[mg][g16]=e+1

#define NBLK 256
#define NTHR 256
#define X_   1024
#define H_   4096
#define T_   64
#define NEV  252

typedef __bf16 bf16_t;
typedef __attribute__((ext_vector_type(8))) __bf16 bf16x8;
typedef __attribute__((ext_vector_type(4))) float  f32x4;
typedef __attribute__((ext_vector_type(2))) uint32_t u32x2;
typedef __attribute__((ext_vector_type(4))) uint32_t u32x4;

// ---- workspace layout (bytes) ----
#define WS_FLAGS 0                          // 512 u32 = 2 KB (memset 4 KB)
#define WS_YIN   4096                       // bf16 [64][1024]  (128 KB)
#define WS_H     (4096 + 131072)            // bf16 [64][4096]  (512 KB)
#define WS_NEED  (4096 + 131072 + 524288)

// -------- write-through coherent stores (L2 is NEVER dirty) ----------------
__device__ inline void store_coh_b16(bf16_t* p, float v) {
  uint32_t d = (uint32_t)__builtin_bit_cast(uint16_t, (bf16_t)v);
  asm volatile("global_store_short %0, %1, off sc0 sc1" :: "v"(p), "v"(d) : "memory");
}
__device__ inline void store_coh_f32(float* p, float v) {
  asm volatile("global_store_dword %0, %1, off sc0 sc1" :: "v"(p), "v"(v) : "memory");
}
__device__ inline void store_coh_b64(bf16_t* p, u32x2 v) {
  asm volatile("global_store_dwordx2 %0, %1, off sc0 sc1" :: "v"(p), "v"(v) : "memory");
}
__device__ inline void store_flag(uint32_t* p, uint32_t v) {
  asm volatile("global_store_dword %0, %1, off sc0 sc1" :: "v"(p), "v"(v) : "memory");
}
__device__ inline uint32_t load_flag(const uint32_t* p) {
  uint32_t v;
  asm volatile("global_load_dword %0, %1, off sc0 sc1\n\ts_waitcnt vmcnt(0)"
               : "=v"(v) : "v"(p) : "memory");
  return v;
}
__device__ inline uint32_t pkbf(float a, float b) {
  return (uint32_t)__builtin_bit_cast(uint16_t, (bf16_t)a)
       | ((uint32_t)__builtin_bit_cast(uint16_t, (bf16_t)b) << 16);
}

// -------- pipelined 32x cached 16B loads + 32 MFMA (2 acc chains) -----------
#define LDG(dst, P, OFF) \
  asm volatile("global_load_dwordx4 %0, %1, off offset:" OFF \
               : "=v"(dst) : "v"(P))
#define DECL8(P) u32x4 P##0, P##1, P##2, P##3, P##4, P##5, P##6, P##7
#define LD8(P, PTR) \
  LDG(P##0, PTR, "0");   LDG(P##1, PTR, "64");  LDG(P##2, PTR, "128"); \
  LDG(P##3, PTR, "192"); LDG(P##4, PTR, "256"); LDG(P##5, PTR, "320"); \
  LDG(P##6, PTR, "384"); LDG(P##7, PTR, "448")
#define WAITV(N) do { asm volatile("s_waitcnt vmcnt(" #N ")" ::: "memory"); \
  __builtin_amdgcn_sched_barrier(0); } while (0)
#define BC(q) __builtin_bit_cast(bf16x8, q)
#define MM8(P, WF, KB) \
  acc0 = __builtin_amdgcn_mfma_f32_16x16x32_bf16(BC(P##0), (WF)[(KB)+0], acc0, 0,0,0); \
  acc1 = __builtin_amdgcn_mfma_f32_16x16x32_bf16(BC(P##1), (WF)[(KB)+1], acc1, 0,0,0); \
  acc0 = __builtin_amdgcn_mfma_f32_16x16x32_bf16(BC(P##2), (WF)[(KB)+2], acc0, 0,0,0); \
  acc1 = __builtin_amdgcn_mfma_f32_16x16x32_bf16(BC(P##3), (WF)[(KB)+3], acc1, 0,0,0); \
  acc0 = __builtin_amdgcn_mfma_f32_16x16x32_bf16(BC(P##4), (WF)[(KB)+4], acc0, 0,0,0); \
  acc1 = __builtin_amdgcn_mfma_f32_16x16x32_bf16(BC(P##5), (WF)[(KB)+5], acc1, 0,0,0); \
  acc0 = __builtin_amdgcn_mfma_f32_16x16x32_bf16(BC(P##6), (WF)[(KB)+6], acc0, 0,0,0); \
  acc1 = __builtin_amdgcn_mfma_f32_16x16x32_bf16(BC(P##7), (WF)[(KB)+7], acc1, 0,0,0)

#define GEMM32(WF, BASEPTR, ACCOUT) do { \
  const bf16_t* _p0 = (BASEPTR); \
  const bf16_t* _p1 = _p0 + 256; const bf16_t* _p2 = _p0 + 512; \
  const bf16_t* _p3 = _p0 + 768; \
  DECL8(qa); DECL8(qb); DECL8(qc); DECL8(qd); \
  f32x4 acc0 = {0.f,0.f,0.f,0.f}, acc1 = {0.f,0.f,0.f,0.f}; \
  LD8(qa, _p0); LD8(qb, _p1); \
  WAITV(8); MM8(qa, WF, 0);  LD8(qc, _p2); \
  WAITV(8); MM8(qb, WF, 8);  LD8(qd, _p3); \
  WAITV(8); MM8(qc, WF, 16); \
  WAITV(0); MM8(qd, WF, 24); \
  ACCOUT = acc0 + acc1; \
} while (0)

// phase entry: wave 0 polls producer flags (one per lane), then performs the
// agent-acquire (buffer_inv; stores are write-through so no data can be lost);
// __syncthreads() orders the inv before all waves' cached loads.
#define PHASE_WAIT(POLLPTR) do { \
  if (w == 0) { \
    uint32_t v = load_flag(POLLPTR); \
    while (v < e) { __builtin_amdgcn_s_sleep(1); v = load_flag(POLLPTR); } \
    asm volatile("buffer_inv sc0 sc1\n\ts_waitcnt vmcnt(0)" ::: "memory"); \
  } \
  __syncthreads(); \
  __builtin_amdgcn_sched_barrier(0); \
} while (0)

__global__ void __launch_bounds__(NTHR, 1) node_rk4_kernel(
    const float* __restrict__ x, const float* __restrict__ ts,
    const float* __restrict__ W1, const float* __restrict__ b1,
    const float* __restrict__ W2, const float* __restrict__ b2,
    float* __restrict__ out, uint8_t* __restrict__ ws)
{
  uint32_t* flags = (uint32_t*)(ws + WS_FLAGS);   // [0..255]=fB, [256..511]=fA
  bf16_t* yin  = (bf16_t*)(ws + WS_YIN);
  bf16_t* hbuf = (bf16_t*)(ws + WS_H);

  const int tid = threadIdx.x;
  const int b   = blockIdx.x;
  const int w   = tid >> 6;    // wave 0..3
  const int l   = tid & 63;
  const int lr  = l & 15;
  const int lh  = l >> 4;
  const int g16 = b >> 2;      // 0..63: column-slice owner
  const int mg  = b & 3;       // 0..3 : row group / independent solve

  uint32_t* fB = flags + mg * 64;          // yin version flags (one per producer)
  uint32_t* fA = flags + 256 + mg * 64;    // h   version flags
  uint32_t* myfB = fB + g16;
  uint32_t* myfA = fA + g16;
  uint32_t* pollB = fB + l;                // wave-0 lane l watches producer l
  uint32_t* pollA = fA + l;

  __shared__ float red[4][64][4];   // A: wave-local transpose; B: cross-wave K-reduce
  __shared__ float tsl[T_];
  if (tid < T_) tsl[tid] = ts[tid];

  // ---- pack W1 B-fragments: wave w owns h-cols [g16*64 + w*16, +16), full K ----
  bf16x8 w1f[32];
  #pragma unroll
  for (int ks = 0; ks < 32; ks++)
    #pragma unroll
    for (int j = 0; j < 8; j++)
      w1f[ks][j] = (bf16_t)W1[(size_t)(ks * 32 + lh * 8 + j) * H_ + g16 * 64 + w * 16 + lr];

  // ---- pack W2 B-fragments: out-cols [g16*16, +16), wave w owns K-quarter w ----
  bf16x8 w2f[32];
  #pragma unroll
  for (int ks = 0; ks < 32; ks++)
    #pragma unroll
    for (int j = 0; j < 8; j++)
      w2f[ks][j] = (bf16_t)W2[(size_t)(w * 1024 + ks * 32 + lh * 8 + j) * X_ + g16 * 16 + lr];

  // ---- per-thread epilogue mapping (one output element per thread) ----
  const int erow  = tid >> 4;
  const int ecol  = tid & 15;
  const int elane = (erow >> 2) * 16 + ecol;   // C/D: col=lane&15, row=(lane>>4)*4+reg
  const int ereg  = erow & 3;
  const int grow  = mg * 16 + erow;            // global batch row
  const int gcol  = g16 * 16 + ecol;           // global X column
  const float bias1 = b1[g16 * 64 + w * 16 + lr];
  const float bias2 = b2[gcol];

  // ---- RK4 state: 1 element per thread, in registers for the whole solve ----
  float y = x[(size_t)grow * X_ + gcol];
  float yac = 0.f;
  store_coh_f32(&out[(size_t)grow * (T_ * X_) + gcol], y);  // pred[:,0,:] = x
  store_coh_b16(yin + (size_t)grow * X_ + gcol, y);         // publish yin v1
  asm volatile("s_waitcnt vmcnt(0)" ::: "memory");
  __syncthreads();
  if (tid == 0) store_flag(myfB, 1u);

  for (int n = 0; n < NEV; n++) {
    const uint32_t e = (uint32_t)n + 1u;
    const int step = n >> 2, ev = n & 3;
    const float dt  = tsl[step + 1] - tsl[step];
    const float dth = 0.5f * dt, dt6 = dt * (1.f / 6.f), dt3 = dt * (1.f / 3.f);

    // ===== phase A: wait yin v(e); h tile = tanh(yin @ W1 + b1) =====
    PHASE_WAIT(pollB);
    {
      f32x4 hacc;
      GEMM32(w1f, yin + (size_t)(mg * 16 + lr) * X_ + lh * 8, hacc);
      hacc[0] = tanhf(hacc[0] + bias1); hacc[1] = tanhf(hacc[1] + bias1);
      hacc[2] = tanhf(hacc[2] + bias1); hacc[3] = tanhf(hacc[3] + bias1);
      *(f32x4*)&red[w][l][0] = hacc;          // wave-local transpose via LDS
      const int trow = l >> 2, tc0 = (l & 3) * 4;
      float v0 = red[w][(trow >> 2) * 16 + tc0 + 0][trow & 3];
      float v1 = red[w][(trow >> 2) * 16 + tc0 + 1][trow & 3];
      float v2 = red[w][(trow >> 2) * 16 + tc0 + 2][trow & 3];
      float v3 = red[w][(trow >> 2) * 16 + tc0 + 3][trow & 3];
      u32x2 pk; pk[0] = pkbf(v0, v1); pk[1] = pkbf(v2, v3);
      store_coh_b64(hbuf + (size_t)(mg * 16 + trow) * H_ + g16 * 64 + w * 16 + tc0, pk);
    }
    asm volatile("s_waitcnt vmcnt(0)" ::: "memory");
    __syncthreads();
    if (tid == 0) store_flag(myfA, e);

    // ===== phase B: wait h v(e); k tile = h @ W2 + b2; RK4 update =====
    PHASE_WAIT(pollA);
    {
      f32x4 kacc;
      GEMM32(w2f, hbuf + (size_t)(mg * 16 + lr) * H_ + w * 1024 + lh * 8, kacc);
      *(f32x4*)&red[w][l][0] = kacc;
      __syncthreads();
      float kv = red[0][elane][ereg] + red[1][elane][ereg]
               + red[2][elane][ereg] + red[3][elane][ereg] + bias2;
      float ypub;
      if (ev == 0)      { yac = y + dt6 * kv; ypub = y + dth * kv; }
      else if (ev == 1) { yac += dt3 * kv;    ypub = y + dth * kv; }
      else if (ev == 2) { yac += dt3 * kv;    ypub = y + dt * kv;  }
      else              { y = yac + dt6 * kv; ypub = y; }
      store_coh_b16(yin + (size_t)grow * X_ + gcol, ypub);
      if (ev == 3)
        store_coh_f32(&out[(size_t)grow * (T_ * X_) + (size_t)(step + 1) * X_ + gcol], y);
    }
    asm volatile("s_waitcnt vmcnt(0)" ::: "memory");
    __syncthreads();
    if (tid == 0) store_flag(myfB, e + 1u);
  }
}

extern "C" void kernel_launch(void* const* d_in, const int* in_sizes, int n_in,
                              void* d_out, int out_size, void* d_ws, size_t ws_size,
                              hipStream_t stream) {
  const float* x  = (const float*)d_in[0];
  const float* ts = (const float*)d_in[1];
  const float* W1 = (const float*)d_in[2];
  const float* b1 = (const float*)d_in[3];
  const float* W2 = (const float*)d_in[4];
  const float* b2 = (const float*)d_in[5];
  float* out = (float*)d_out;
  uint8_t* ws = (uint8_t*)d_ws;
  if (ws_size < (size_t)WS_NEED) return;
  hipMemsetAsync(d_ws, 0, 4096, stream);  // reset flag lines every launch

  void* args[] = {(void*)&x, (void*)&ts, (void*)&W1, (void*)&b1,
                  (void*)&W2, (void*)&b2, (void*)&out, (void*)&ws};
  hipError_t err = hipLaunchCooperativeKernel((void*)node_rk4_kernel,
                                              dim3(NBLK), dim3(NTHR), args, 0, stream);
  if (err != hipSuccess) {
    node_rk4_kernel<<<dim3(NBLK), dim3(NTHR), 0, stream>>>(x, ts, W1, b1, W2, b2, out, ws);
  }
}

// Round 8
// 2083.957 us; speedup vs baseline: 2.0445x; 2.0445x over previous
//
#include <hip/hip_runtime.h>
#include <hip/hip_bf16.h>
#include <cstdint>

// Neural-ODE RK4, v8: v6 dataflow with 3.5x less coherent-fabric traffic.
// v6 was fabric-BW-bound: 64 MB/eval of sc0sc1 reads at ~4.8 TB/s = 13.3us/eval.
// v8: (1) phase-A waves SPLIT K (no 4x duplicate yin read; cross-wave LDS
// reduce before tanh); (2) phase-B is block-level split-K: block (c,q,mg)
// computes a 16x64 fp32 partial over K-chunk [1024q,+1024) reading 32 KB of h
// (not 128 KB); the q==0 owner holds RK4 state, sums 3 peer partials + own,
// publishes yin. Traffic: 64 -> ~18 MB/eval. One extra flag hop (partial ->
// owner), fan-ins 16/16/3. All flags single-writer monotone epochs; all
// cross-block data sc0 sc1 write-through (L2 never dirty).
// Anti-dep proof: owner's yin(e+1) write is transitively after fA(e) of ALL 64
// A-readers (own B waits fA[0..15], peers cover 16..63); A(e+1) waits all 16
// owners' fB; peer partial slot(e+1) rewrite is after owner's fB(e+1).

#define NBLK 256
#define NTHR 256
#define X_   1024
#define H_   4096
#define T_   64
#define NEV  252

typedef __bf16 bf16_t;
typedef __attribute__((ext_vector_type(8))) __bf16 bf16x8;
typedef __attribute__((ext_vector_type(4))) float  f32x4;
typedef __attribute__((ext_vector_type(2))) uint32_t u32x2;
typedef __attribute__((ext_vector_type(4))) uint32_t u32x4;

// ---- workspace layout (bytes) ----
#define WS_FLAGS 0                            // 512 slots * 64B = 32 KB
#define WS_YIN   32768                        // bf16 [64][1024]   (128 KB)
#define WS_H     (32768 + 131072)             // bf16 [64][4096]   (512 KB)
#define WS_P     (32768 + 131072 + 524288)    // f32 partials      (768 KB)
#define WS_NEED  (WS_P + 786432)
// flag slot indices (u32 stride 16 = 64 B apart):
//   fA: 0   + mg*64 + g16          (A published h cols [64g16,+64), eval e)
//   fB: 256 + mg*16 + c            (owner published yin cols [64c,+64), eval e)
//   fP: 320 + (mg*16+c)*3 + (q-1)  (peer q published partial, eval e)

// -------- coherent ops (cross-block data at the L3 coherence point) --------
__device__ inline void store_coh_b16(bf16_t* p, float v) {
  uint32_t d = (uint32_t)__builtin_bit_cast(uint16_t, (bf16_t)v);
  asm volatile("global_store_short %0, %1, off sc0 sc1" :: "v"(p), "v"(d) : "memory");
}
__device__ inline void store_coh_f32(float* p, float v) {
  asm volatile("global_store_dword %0, %1, off sc0 sc1" :: "v"(p), "v"(v) : "memory");
}
__device__ inline void store_coh_b64(bf16_t* p, u32x2 v) {
  asm volatile("global_store_dwordx2 %0, %1, off sc0 sc1" :: "v"(p), "v"(v) : "memory");
}
__device__ inline void store_coh_f32x4(float* p, f32x4 v) {
  asm volatile("global_store_dwordx4 %0, %1, off sc0 sc1" :: "v"(p), "v"(v) : "memory");
}
__device__ inline void store_flag(uint32_t* p, uint32_t v) {
  asm volatile("global_store_dword %0, %1, off sc0 sc1" :: "v"(p), "v"(v) : "memory");
}
__device__ inline uint32_t load_flag(const uint32_t* p) {
  uint32_t v;
  asm volatile("global_load_dword %0, %1, off sc0 sc1\n\ts_waitcnt vmcnt(0)"
               : "=v"(v) : "v"(p) : "memory");
  return v;
}
__device__ inline void load3_coh(const float* p0, const float* p1, const float* p2,
                                 f32x4& a, f32x4& b, f32x4& c) {
  asm volatile(
      "global_load_dwordx4 %0, %3, off sc0 sc1\n\t"
      "global_load_dwordx4 %1, %4, off sc0 sc1\n\t"
      "global_load_dwordx4 %2, %5, off sc0 sc1\n\t"
      "s_waitcnt vmcnt(0)"
      : "=&v"(a), "=&v"(b), "=&v"(c)
      : "v"(p0), "v"(p1), "v"(p2) : "memory");
}
__device__ inline uint32_t pkbf(float a, float b) {
  return (uint32_t)__builtin_bit_cast(uint16_t, (bf16_t)a)
       | ((uint32_t)__builtin_bit_cast(uint16_t, (bf16_t)b) << 16);
}

#define LDG(dst, P, OFF) \
  asm volatile("global_load_dwordx4 %0, %1, off offset:" OFF " sc0 sc1" \
               : "=v"(dst) : "v"(P))
#define DECL8(P) u32x4 P##0, P##1, P##2, P##3, P##4, P##5, P##6, P##7
#define LD8(P, PTR) \
  LDG(P##0, PTR, "0");   LDG(P##1, PTR, "64");  LDG(P##2, PTR, "128"); \
  LDG(P##3, PTR, "192"); LDG(P##4, PTR, "256"); LDG(P##5, PTR, "320"); \
  LDG(P##6, PTR, "384"); LDG(P##7, PTR, "448")
#define WAITV0 do { asm volatile("s_waitcnt vmcnt(0)" ::: "memory"); \
  __builtin_amdgcn_sched_barrier(0); } while (0)
#define BC(q) __builtin_bit_cast(bf16x8, q)

#define POLL(SLOTEXPR, NLANES, TARGET) do { \
  if (w == 0 && l < (NLANES)) { \
    uint32_t* _p = flags + (SLOTEXPR) * 16; \
    uint32_t _v = load_flag(_p); \
    while (_v < (TARGET)) { __builtin_amdgcn_s_sleep(1); _v = load_flag(_p); } \
  } \
  __syncthreads(); \
  __builtin_amdgcn_sched_barrier(0); \
} while (0)

__global__ void __launch_bounds__(NTHR, 1) node_rk4_kernel(
    const float* __restrict__ x, const float* __restrict__ ts,
    const float* __restrict__ W1, const float* __restrict__ b1,
    const float* __restrict__ W2, const float* __restrict__ b2,
    float* __restrict__ out, uint8_t* __restrict__ ws)
{
  uint32_t* flags = (uint32_t*)(ws + WS_FLAGS);
  bf16_t* yin  = (bf16_t*)(ws + WS_YIN);
  bf16_t* hbuf = (bf16_t*)(ws + WS_H);
  float*  pbuf = (float*)(ws + WS_P);

  const int tid = threadIdx.x;
  const int b   = blockIdx.x;
  const int w   = tid >> 6;    // wave 0..3
  const int l   = tid & 63;
  const int lr  = l & 15;
  const int lh  = l >> 4;
  const int g16 = b >> 2;      // 0..63
  const int mg  = b & 3;       // row group (independent solve), rows [16mg,+16)
  const int c   = g16 & 15;    // B-role: out-col group [64c,+64)
  const int q   = g16 >> 4;    // B-role: K-chunk [1024q,+1024); q==0 owns RK4

  __shared__ float red[4][4][64][4];   // [wave][ct][lane][4] cross-wave reduce (16 KB)
  __shared__ float tr[4][64][4];       // per-wave transpose scratch (4 KB)
  __shared__ float tsl[T_];
  if (tid < T_) tsl[tid] = ts[tid];

  // ---- pack W1/W2 B-fragments (waves split K into 256-chunks) ----
  // w1f[ct][ks]: W1[K=w*256+ks*32+lh*8+j][col=g16*64+ct*16+lr]   (128 VGPRs)
  // w2f[ct][ks]: W2[K=q*1024+w*256+ks*32+lh*8+j][col=c*64+ct*16+lr] (128 VGPRs)
  bf16x8 w1f[4][8], w2f[4][8];
  #pragma unroll
  for (int ct = 0; ct < 4; ct++)
    #pragma unroll
    for (int ks = 0; ks < 8; ks++)
      #pragma unroll
      for (int j = 0; j < 8; j++) {
        w1f[ct][ks][j] = (bf16_t)W1[(size_t)(w*256 + ks*32 + lh*8 + j) * H_ + g16*64 + ct*16 + lr];
        w2f[ct][ks][j] = (bf16_t)W2[(size_t)(q*1024 + w*256 + ks*32 + lh*8 + j) * X_ + c*64 + ct*16 + lr];
      }

  const float bias1 = b1[g16*64 + w*16 + lr];   // A epilogue: wave w owns ct==w
  const float bias2 = b2[c*64 + w*16 + lr];     // B owner: wave w owns ct==w

  // ---- RK4 state (owners only): f32x4 in C/D layout:
  //      row = mg*16 + lh*4 + r, col = c*64 + w*16 + lr ----
  f32x4 y = {0.f,0.f,0.f,0.f}, yac = {0.f,0.f,0.f,0.f};
  if (q == 0) {
    #pragma unroll
    for (int r = 0; r < 4; r++) {
      const int row = mg*16 + lh*4 + r, col = c*64 + w*16 + lr;
      y[r] = x[(size_t)row * X_ + col];
      store_coh_f32(&out[(size_t)row * (T_ * X_) + col], y[r]);  // pred[:,0,:]
      store_coh_b16(yin + (size_t)row * X_ + col, y[r]);
    }
    asm volatile("s_waitcnt vmcnt(0)" ::: "memory");
    __syncthreads();
    if (tid == 0) store_flag(flags + (256 + mg*16 + c) * 16, 1u);
  }

  for (int n = 0; n < NEV; n++) {
    const uint32_t e = (uint32_t)n + 1u;
    const int step = n >> 2, ev = n & 3;
    const float dt  = tsl[step + 1] - tsl[step];
    const float dth = 0.5f * dt, dt6 = dt * (1.f / 6.f), dt3 = dt * (1.f / 3.f);

    // ===== phase A: wait 16 owner fB flags; h tile = tanh(yin @ W1 + b1) =====
    POLL(256 + mg*16 + l, 16, e);
    {
      bf16x8 af[8];
      {
        DECL8(qa);
        const bf16_t* ap = yin + (size_t)(mg*16 + lr) * X_ + w*256 + lh*8;
        LD8(qa, ap);
        WAITV0;
        af[0]=BC(qa0); af[1]=BC(qa1); af[2]=BC(qa2); af[3]=BC(qa3);
        af[4]=BC(qa4); af[5]=BC(qa5); af[6]=BC(qa6); af[7]=BC(qa7);
      }
      #pragma unroll
      for (int ct = 0; ct < 4; ct++) {
        f32x4 a = {0.f,0.f,0.f,0.f};
        #pragma unroll
        for (int ks = 0; ks < 8; ks++)
          a = __builtin_amdgcn_mfma_f32_16x16x32_bf16(af[ks], w1f[ct][ks], a, 0, 0, 0);
        *(f32x4*)&red[w][ct][l][0] = a;
      }
      __syncthreads();
      f32x4 h4;
      #pragma unroll
      for (int r = 0; r < 4; r++)
        h4[r] = tanhf(red[0][w][l][r] + red[1][w][l][r] + red[2][w][l][r] + red[3][w][l][r] + bias1);
      *(f32x4*)&tr[w][l][0] = h4;
      const int trow = l >> 2, tc0 = (l & 3) * 4;
      float v0 = tr[w][(trow >> 2) * 16 + tc0 + 0][trow & 3];
      float v1 = tr[w][(trow >> 2) * 16 + tc0 + 1][trow & 3];
      float v2 = tr[w][(trow >> 2) * 16 + tc0 + 2][trow & 3];
      float v3 = tr[w][(trow >> 2) * 16 + tc0 + 3][trow & 3];
      u32x2 pk; pk[0] = pkbf(v0, v1); pk[1] = pkbf(v2, v3);
      store_coh_b64(hbuf + (size_t)(mg*16 + trow) * H_ + g16*64 + w*16 + tc0, pk);
    }
    asm volatile("s_waitcnt vmcnt(0)" ::: "memory");
    __syncthreads();
    if (tid == 0) store_flag(flags + (mg*64 + g16) * 16, e);

    // ===== phase B: wait 16 fA flags of my K-chunk; partial = h @ W2chunk =====
    POLL(mg*64 + q*16 + l, 16, e);
    f32x4 p4;
    {
      bf16x8 bfr[8];
      {
        DECL8(qb);
        const bf16_t* bp = hbuf + (size_t)(mg*16 + lr) * H_ + q*1024 + w*256 + lh*8;
        LD8(qb, bp);
        WAITV0;
        bfr[0]=BC(qb0); bfr[1]=BC(qb1); bfr[2]=BC(qb2); bfr[3]=BC(qb3);
        bfr[4]=BC(qb4); bfr[5]=BC(qb5); bfr[6]=BC(qb6); bfr[7]=BC(qb7);
      }
      #pragma unroll
      for (int ct = 0; ct < 4; ct++) {
        f32x4 a = {0.f,0.f,0.f,0.f};
        #pragma unroll
        for (int ks = 0; ks < 8; ks++)
          a = __builtin_amdgcn_mfma_f32_16x16x32_bf16(bfr[ks], w2f[ct][ks], a, 0, 0, 0);
        *(f32x4*)&red[w][ct][l][0] = a;
      }
      __syncthreads();
      #pragma unroll
      for (int r = 0; r < 4; r++)
        p4[r] = red[0][w][l][r] + red[1][w][l][r] + red[2][w][l][r] + red[3][w][l][r];
    }

    if (q != 0) {
      // peer: publish fp32 partial (C/D layout), flag fP
      float* ps = pbuf + ((size_t)(mg*16 + c) * 3 + (q - 1)) * 1024 + w*256 + l*4;
      store_coh_f32x4(ps, p4);
      asm volatile("s_waitcnt vmcnt(0)" ::: "memory");
      __syncthreads();
      if (tid == 0) store_flag(flags + (320 + (mg*16 + c) * 3 + (q - 1)) * 16, e);
    } else {
      // owner: wait 3 peer partials, sum, RK4, publish yin
      POLL(320 + (mg*16 + c) * 3 + l, 3, e);
      const float* pb = pbuf + (size_t)(mg*16 + c) * 3 * 1024 + w*256 + l*4;
      f32x4 pa_, pb_, pc_;
      load3_coh(pb, pb + 1024, pb + 2048, pa_, pb_, pc_);
      #pragma unroll
      for (int r = 0; r < 4; r++) {
        const float kv = p4[r] + pa_[r] + pb_[r] + pc_[r] + bias2;
        float ypub;
        if (ev == 0)      { yac[r] = y[r] + dt6 * kv; ypub = y[r] + dth * kv; }
        else if (ev == 1) { yac[r] += dt3 * kv;       ypub = y[r] + dth * kv; }
        else if (ev == 2) { yac[r] += dt3 * kv;       ypub = y[r] + dt * kv;  }
        else              { y[r] = yac[r] + dt6 * kv; ypub = y[r]; }
        const int row = mg*16 + lh*4 + r, col = c*64 + w*16 + lr;
        store_coh_b16(yin + (size_t)row * X_ + col, ypub);
        if (ev == 3)
          store_coh_f32(&out[(size_t)row * (T_ * X_) + (size_t)(step + 1) * X_ + col], y[r]);
      }
      asm volatile("s_waitcnt vmcnt(0)" ::: "memory");
      __syncthreads();
      if (tid == 0) store_flag(flags + (256 + mg*16 + c) * 16, e + 1u);
    }
  }
}

extern "C" void kernel_launch(void* const* d_in, const int* in_sizes, int n_in,
                              void* d_out, int out_size, void* d_ws, size_t ws_size,
                              hipStream_t stream) {
  const float* x  = (const float*)d_in[0];
  const float* ts = (const float*)d_in[1];
  const float* W1 = (const float*)d_in[2];
  const float* b1 = (const float*)d_in[3];
  const float* W2 = (const float*)d_in[4];
  const float* b2 = (const float*)d_in[5];
  float* out = (float*)d_out;
  uint8_t* ws = (uint8_t*)d_ws;
  if (ws_size < (size_t)WS_NEED) return;
  hipMemsetAsync(d_ws, 0, 32768, stream);  // reset all flag lines every launch

  void* args[] = {(void*)&x, (void*)&ts, (void*)&W1, (void*)&b1,
                  (void*)&W2, (void*)&b2, (void*)&out, (void*)&ws};
  hipError_t err = hipLaunchCooperativeKernel((void*)node_rk4_kernel,
                                              dim3(NBLK), dim3(NTHR), args, 0, stream);
  if (err != hipSuccess) {
    node_rk4_kernel<<<dim3(NBLK), dim3(NTHR), 0, stream>>>(x, ts, W1, b1, W2, b2, out, ws);
  }
}